// Round 1
// baseline (517.443 us; speedup 1.0000x reference)
//
#include <hip/hip_runtime.h>

// Problem: B=16, T=2048, D=512, H=512, K=2
// M = B*T = 32768 rows, GEMM K-dim = D*K = 1024, N = 3H = 1536.
//
// ws layout (bytes):
//   Abf [32768][1024] bf16 @ 0          (67,108,864)   -- dead after GEMM; scan
//                                                         scratch (P/C/I, 3MB) overlays it
//   Bbf [1536][1024]  bf16 @ 67108864   ( 3,145,728)
//   GT  [1536][32768] bf16 @ 70254592   (100,663,296)  pre-activation, TRANSPOSED
// total 170,917,888 B

#define MTOT 32768
#define NTOT 1536
#define KTOT 1024
#define DCH  512
#define TLEN 2048
#define NB   16

// scan decomposition: chunks of LC2 steps, two-level (aggregate / combine / apply)
#define LC2    64                 // t per chunk
#define NCH    32                 // TLEN / LC2
#define CHAINS 8192               // NB * DCH chains

typedef __bf16 bf16x8 __attribute__((ext_vector_type(8)));
typedef float  f32x4  __attribute__((ext_vector_type(4)));

__device__ __forceinline__ unsigned short f2bf(float x) {
    unsigned u = __float_as_uint(x);
    u += 0x7FFFu + ((u >> 16) & 1u);   // round-to-nearest-even
    return (unsigned short)(u >> 16);
}
__device__ __forceinline__ float bf2f(unsigned short h) {
    return __uint_as_float(((unsigned)h) << 16);
}
__device__ __forceinline__ float sigmoidf_(float x) {
    return 1.f / (1.f + __expf(-x));
}

// ---------------------------------------------------------------------------
// K0: build A bf16 [M][1024]: A[m][j] = in[(m-1)*512 + j], zero when t==0 && j<512
__global__ __launch_bounds__(256) void make_A(const float* __restrict__ in,
                                              unsigned short* __restrict__ A) {
    size_t i = (size_t)blockIdx.x * 256 + threadIdx.x;
    size_t e = i * 8;
    size_t m = e >> 10;
    int    j = (int)(e & 1023);
    alignas(16) unsigned short h[8];
    if (((m & (TLEN - 1)) == 0) && (j < DCH)) {
#pragma unroll
        for (int r = 0; r < 8; ++r) h[r] = 0;
    } else {
        const float* src = in + ((long long)m - 1) * DCH + j;
        float4 a = *(const float4*)src;
        float4 b = *(const float4*)(src + 4);
        h[0] = f2bf(a.x); h[1] = f2bf(a.y); h[2] = f2bf(a.z); h[3] = f2bf(a.w);
        h[4] = f2bf(b.x); h[5] = f2bf(b.y); h[6] = f2bf(b.z); h[7] = f2bf(b.w);
    }
    *(int4*)(A + e) = *(const int4*)h;
}

// ---------------------------------------------------------------------------
// K1: build B bf16 [N][1024]: Bt[o][kc*512 + d] = w[o*1024 + d*2 + kc]
__global__ __launch_bounds__(256) void make_B(const float* __restrict__ w,
                                              unsigned short* __restrict__ Bt) {
    int i = blockIdx.x * 256 + threadIdx.x;     // 1536*512 = 786432
    int o = i >> 9, d = i & 511;
    float w0 = w[(size_t)(o * 512 + d) * 2];
    float w1 = w[(size_t)(o * 512 + d) * 2 + 1];
    Bt[(size_t)o * 1024 + d]       = f2bf(w0);
    Bt[(size_t)o * 1024 + 512 + d] = f2bf(w1);
}

// ---------------------------------------------------------------------------
// K2: GEMM, output TRANSPOSED: GT[n][m] = sum_k A[m][k]*Bt[n][k] + bias[n] (bf16)
// 128x128 tile, BK=32, 4 waves x (4x4) 16x16x32 bf16 MFMA, global_load_lds
// staging with XOR swizzle folded into the global address (LDS stays lane-linear).
// XCD-aware bijective swizzle: grid 3072 = 8 XCD * 384, so the 12 blocks sharing
// one A panel land on the same XCD's L2.
__global__ __launch_bounds__(256) void gemm_gates(const unsigned short* __restrict__ A,
                                                  const unsigned short* __restrict__ B,
                                                  const float* __restrict__ bias,
                                                  unsigned short* __restrict__ GT) {
    __shared__ int4 sA[512];   // 128 rows x 64B
    __shared__ int4 sB[512];

    const int tid = threadIdx.x;
    const int bx0 = blockIdx.x;
    const int bx  = (bx0 & 7) * 384 + (bx0 >> 3);   // bijective: 3072 % 8 == 0
    const int mT  = bx / 12, nT = bx % 12;
    const int m0  = mT * 128, n0 = nT * 128;

    const int mloc = tid >> 2;
    const int qsw  = (tid & 3) ^ ((mloc >> 1) & 3);
    const unsigned short* ga0 = A + (size_t)(m0 + mloc) * 1024 + qsw * 8;
    const unsigned short* ga1 = A + (size_t)(m0 + 64 + mloc) * 1024 + qsw * 8;
    const unsigned short* gb0 = B + (size_t)(n0 + mloc) * 1024 + qsw * 8;
    const unsigned short* gb1 = B + (size_t)(n0 + 64 + mloc) * 1024 + qsw * 8;

    char* la0 = (char*)sA + tid * 16;
    char* la1 = (char*)sA + 4096 + tid * 16;
    char* lb0 = (char*)sB + tid * 16;
    char* lb1 = (char*)sB + 4096 + tid * 16;

    const int lane = tid & 63;
    const int wv   = tid >> 6;
    const int wm   = (wv & 1) * 64, wn = (wv >> 1) * 64;
    const int lr   = lane & 15, lq = lane >> 4;

    int sAidx[4], sBidx[4];
#pragma unroll
    for (int i = 0; i < 4; ++i) {
        int mi = wm + 16 * i + lr;
        sAidx[i] = mi * 4 + (lq ^ ((mi >> 1) & 3));
        int ni = wn + 16 * i + lr;
        sBidx[i] = ni * 4 + (lq ^ ((ni >> 1) & 3));
    }

    f32x4 acc[4][4] = {};

    for (int kt = 0; kt < KTOT; kt += 32) {
        __builtin_amdgcn_global_load_lds(
            (__attribute__((address_space(1))) void*)(void*)ga0,
            (__attribute__((address_space(3))) void*)la0, 16, 0, 0);
        __builtin_amdgcn_global_load_lds(
            (__attribute__((address_space(1))) void*)(void*)ga1,
            (__attribute__((address_space(3))) void*)la1, 16, 0, 0);
        __builtin_amdgcn_global_load_lds(
            (__attribute__((address_space(1))) void*)(void*)gb0,
            (__attribute__((address_space(3))) void*)lb0, 16, 0, 0);
        __builtin_amdgcn_global_load_lds(
            (__attribute__((address_space(1))) void*)(void*)gb1,
            (__attribute__((address_space(3))) void*)lb1, 16, 0, 0);
        ga0 += 32; ga1 += 32; gb0 += 32; gb1 += 32;
        __syncthreads();

        bf16x8 af[4], bfr[4];
#pragma unroll
        for (int i = 0; i < 4; ++i) af[i]  = __builtin_bit_cast(bf16x8, sA[sAidx[i]]);
#pragma unroll
        for (int j = 0; j < 4; ++j) bfr[j] = __builtin_bit_cast(bf16x8, sB[sBidx[j]]);

#pragma unroll
        for (int i = 0; i < 4; ++i)
#pragma unroll
            for (int j = 0; j < 4; ++j)
                acc[i][j] = __builtin_amdgcn_mfma_f32_16x16x32_bf16(af[i], bfr[j],
                                                                    acc[i][j], 0, 0, 0);
        __syncthreads();
    }

    // epilogue: C/D layout col=lane&15, row=(lane>>4)*4+r.
    // Transposed store: lane's 4 regs are 4 consecutive m -> one ushort4 (8B).
#pragma unroll
    for (int j = 0; j < 4; ++j) {
        int gn = n0 + wn + 16 * j + lr;
        float bj = bias[gn];
#pragma unroll
        for (int i = 0; i < 4; ++i) {
            int rowb = m0 + wm + 16 * i + lq * 4;
            alignas(8) unsigned short pk[4];
#pragma unroll
            for (int r = 0; r < 4; ++r) pk[r] = f2bf(acc[i][j][r] + bj);
            *(int2*)(GT + (size_t)gn * MTOT + rowb) = *(const int2*)pk;
        }
    }
}

// ---------------------------------------------------------------------------
// Scan, 3-kernel two-level decomposition for occupancy.
// S1: per-chunk aggregates.  Block = 256 thr = 32 h x 8 chunks; each thread does
//     a 64-step chunk. Grid = 16 b * 16 hgroups * 4 tgroups = 1024 blocks
//     (4 blocks/CU, 16 waves/CU vs the old fused kernel's 4 waves/CU).
__global__ __launch_bounds__(256) void scan_part1(const unsigned short* __restrict__ GT,
                                                  float* __restrict__ Pws,
                                                  float* __restrict__ Cws) {
    const int tid   = threadIdx.x;
    const int h_loc = tid & 31;
    const int sc    = tid >> 5;           // 0..7
    const int bid   = blockIdx.x;
    const int tg    = bid & 3;
    const int hg    = (bid >> 2) & 15;
    const int b     = bid >> 6;
    const int h     = hg * 32 + h_loc;
    const int cg    = tg * 8 + sc;        // chunk index 0..31

    const size_t mbase = (size_t)b * TLEN + (size_t)cg * LC2;
    const unsigned short* gz = GT + (size_t)h * MTOT + mbase;
    const unsigned short* gf = GT + (size_t)(DCH + h) * MTOT + mbase;

    float P = 1.f, c = 0.f;
    for (int k = 0; k < LC2; k += 8) {
        bf16x8 zv = *(const bf16x8*)(gz + k);
        bf16x8 fv = *(const bf16x8*)(gf + k);
#pragma unroll
        for (int r = 0; r < 8; ++r) {
            float f = sigmoidf_((float)fv[r]);
            float z = 2.f * sigmoidf_(2.f * (float)zv[r]) - 1.f;   // tanh
            c = f * c + (1.f - f) * z;
            P *= f;
        }
    }
    const int ch = b * DCH + h;           // chain index, [cg][ch] layout -> coalesced
    Pws[(size_t)cg * CHAINS + ch] = P;
    Cws[(size_t)cg * CHAINS + ch] = c;
}

// S2: exclusive scan over the 32 chunk aggregates of each chain.
//     8192 chains, one thread each; all loads/stores wave-coalesced.
__global__ __launch_bounds__(256) void scan_part2(const float* __restrict__ Pws,
                                                  const float* __restrict__ Cws,
                                                  float* __restrict__ Iws) {
    const int ch = blockIdx.x * 256 + threadIdx.x;   // 0..8191
    float cc = 0.f;
#pragma unroll
    for (int cg = 0; cg < NCH; ++cg) {
        size_t idx = (size_t)cg * CHAINS + ch;
        Iws[idx] = cc;
        cc = Pws[idx] * cc + Cws[idx];
    }
}

// S3: apply pass — recompute each chunk with the correct carry-in, write outputs.
//     Same 1024-block decomposition as S1; 32 consecutive h per half-wave keeps
//     output stores in 128 B segments.
__global__ __launch_bounds__(256) void scan_part3(const unsigned short* __restrict__ GT,
                                                  const float* __restrict__ Iws,
                                                  float* __restrict__ out) {
    const int tid   = threadIdx.x;
    const int h_loc = tid & 31;
    const int sc    = tid >> 5;
    const int bid   = blockIdx.x;
    const int tg    = bid & 3;
    const int hg    = (bid >> 2) & 15;
    const int b     = bid >> 6;
    const int h     = hg * 32 + h_loc;
    const int cg    = tg * 8 + sc;

    const size_t mbase = (size_t)b * TLEN + (size_t)cg * LC2;
    const unsigned short* gz = GT + (size_t)h * MTOT + mbase;
    const unsigned short* gf = GT + (size_t)(DCH + h) * MTOT + mbase;
    const unsigned short* go = GT + (size_t)(2 * DCH + h) * MTOT + mbase;

    const int ch = b * DCH + h;
    float c = Iws[(size_t)cg * CHAINS + ch];

    const size_t BTH = (size_t)NB * TLEN * DCH;
    float* oC  = out + mbase * DCH + h;
    float* oOC = oC + BTH;
    for (int k = 0; k < LC2; k += 8) {
        bf16x8 zv = *(const bf16x8*)(gz + k);
        bf16x8 fv = *(const bf16x8*)(gf + k);
        bf16x8 ov = *(const bf16x8*)(go + k);
#pragma unroll
        for (int r = 0; r < 8; ++r) {
            float f = sigmoidf_((float)fv[r]);
            float z = 2.f * sigmoidf_(2.f * (float)zv[r]) - 1.f;
            float o = sigmoidf_((float)ov[r]);
            c = f * c + (1.f - f) * z;
            oC[(size_t)(k + r) * DCH]  = c;
            oOC[(size_t)(k + r) * DCH] = o * c;
        }
    }
}

// ---------------------------------------------------------------------------
extern "C" void kernel_launch(void* const* d_in, const int* in_sizes, int n_in,
                              void* d_out, int out_size, void* d_ws, size_t ws_size,
                              hipStream_t stream) {
    const float* in   = (const float*)d_in[0];   // [16,2048,512] f32
    const float* w    = (const float*)d_in[1];   // [1536,512,2] f32
    const float* bias = (const float*)d_in[2];   // [1536] f32
    float* out = (float*)d_out;                  // [2][16,2048,512] f32

    unsigned short* Abf = (unsigned short*)d_ws;
    unsigned short* Bbf = Abf + (size_t)MTOT * 1024;
    unsigned short* GT  = Bbf + (size_t)NTOT * 1024;

    // scan scratch overlays Abf (dead after the GEMM): 3 * 1 MB
    float* Pws = (float*)d_ws;
    float* Cws = Pws + (size_t)NCH * CHAINS;
    float* Iws = Cws + (size_t)NCH * CHAINS;

    make_A<<<dim3(16384), dim3(256), 0, stream>>>(in, Abf);
    make_B<<<dim3(3072),  dim3(256), 0, stream>>>(w, Bbf);
    gemm_gates<<<dim3(3072), dim3(256), 0, stream>>>(Abf, Bbf, bias, GT);
    scan_part1<<<dim3(1024), dim3(256), 0, stream>>>(GT, Pws, Cws);
    scan_part2<<<dim3(CHAINS / 256), dim3(256), 0, stream>>>(Pws, Cws, Iws);
    scan_part3<<<dim3(1024), dim3(256), 0, stream>>>(GT, Iws, out);
}

// Round 2
// 418.590 us; speedup vs baseline: 1.2362x; 1.2362x over previous
//
#include <hip/hip_runtime.h>

// Problem: B=16, T=2048, D=512, H=512, K=2
// M = B*T = 32768 rows, GEMM K-dim = D*K = 1024, N = 3H = 1536.
//
// ws layout (bytes):
//   Abf [32768][1024] bf16 @ 0          (67,108,864)   -- dead after GEMM; scan
//                                                         scratch (P/C/I, 3MB) overlays it
//   Bbf [1536][1024]  bf16 @ 67108864   ( 3,145,728)
//   GT  [1536][32768] bf16 @ 70254592   (100,663,296)  pre-activation, TRANSPOSED
// total 170,917,888 B

#define MTOT 32768
#define NTOT 1536
#define KTOT 1024
#define DCH  512
#define TLEN 2048
#define NB   16

// scan decomposition: chunks of LC2 steps, two-level (aggregate / combine / apply)
#define LC2    64                 // t per chunk
#define NCH    32                 // TLEN / LC2
#define CHAINS 8192               // NB * DCH chains

typedef __bf16 bf16x8 __attribute__((ext_vector_type(8)));
typedef float  f32x4  __attribute__((ext_vector_type(4)));

__device__ __forceinline__ unsigned short f2bf(float x) {
    unsigned u = __float_as_uint(x);
    u += 0x7FFFu + ((u >> 16) & 1u);   // round-to-nearest-even
    return (unsigned short)(u >> 16);
}
__device__ __forceinline__ float bf2f(unsigned short h) {
    return __uint_as_float(((unsigned)h) << 16);
}
__device__ __forceinline__ float sigmoidf_(float x) {
    return 1.f / (1.f + __expf(-x));
}

// ---------------------------------------------------------------------------
// K0: build A bf16 [M][1024]: A[m][j] = in[(m-1)*512 + j], zero when t==0 && j<512
__global__ __launch_bounds__(256) void make_A(const float* __restrict__ in,
                                              unsigned short* __restrict__ A) {
    size_t i = (size_t)blockIdx.x * 256 + threadIdx.x;
    size_t e = i * 8;
    size_t m = e >> 10;
    int    j = (int)(e & 1023);
    alignas(16) unsigned short h[8];
    if (((m & (TLEN - 1)) == 0) && (j < DCH)) {
#pragma unroll
        for (int r = 0; r < 8; ++r) h[r] = 0;
    } else {
        const float* src = in + ((long long)m - 1) * DCH + j;
        float4 a = *(const float4*)src;
        float4 b = *(const float4*)(src + 4);
        h[0] = f2bf(a.x); h[1] = f2bf(a.y); h[2] = f2bf(a.z); h[3] = f2bf(a.w);
        h[4] = f2bf(b.x); h[5] = f2bf(b.y); h[6] = f2bf(b.z); h[7] = f2bf(b.w);
    }
    *(int4*)(A + e) = *(const int4*)h;
}

// ---------------------------------------------------------------------------
// K1: build B bf16 [N][1024]: Bt[o][kc*512 + d] = w[o*1024 + d*2 + kc]
__global__ __launch_bounds__(256) void make_B(const float* __restrict__ w,
                                              unsigned short* __restrict__ Bt) {
    int i = blockIdx.x * 256 + threadIdx.x;     // 1536*512 = 786432
    int o = i >> 9, d = i & 511;
    float w0 = w[(size_t)(o * 512 + d) * 2];
    float w1 = w[(size_t)(o * 512 + d) * 2 + 1];
    Bt[(size_t)o * 1024 + d]       = f2bf(w0);
    Bt[(size_t)o * 1024 + 512 + d] = f2bf(w1);
}

// ---------------------------------------------------------------------------
// K2: GEMM, output TRANSPOSED: GT[n][m] = sum_k A[m][k]*Bt[n][k] + bias[n] (bf16)
// 128x128 tile, BK=32, 4 waves x (4x4) 16x16x32 bf16 MFMA, global_load_lds
// staging with XOR swizzle folded into the global address (LDS stays lane-linear).
// XCD-aware bijective swizzle: grid 3072 = 8 XCD * 384, so the 12 blocks sharing
// one A panel land on the same XCD's L2 (FETCH 274 MB -> 82 MB, measured R1).
__global__ __launch_bounds__(256) void gemm_gates(const unsigned short* __restrict__ A,
                                                  const unsigned short* __restrict__ B,
                                                  const float* __restrict__ bias,
                                                  unsigned short* __restrict__ GT) {
    __shared__ int4 sA[512];   // 128 rows x 64B
    __shared__ int4 sB[512];

    const int tid = threadIdx.x;
    const int bx0 = blockIdx.x;
    const int bx  = (bx0 & 7) * 384 + (bx0 >> 3);   // bijective: 3072 % 8 == 0
    const int mT  = bx / 12, nT = bx % 12;
    const int m0  = mT * 128, n0 = nT * 128;

    const int mloc = tid >> 2;
    const int qsw  = (tid & 3) ^ ((mloc >> 1) & 3);
    const unsigned short* ga0 = A + (size_t)(m0 + mloc) * 1024 + qsw * 8;
    const unsigned short* ga1 = A + (size_t)(m0 + 64 + mloc) * 1024 + qsw * 8;
    const unsigned short* gb0 = B + (size_t)(n0 + mloc) * 1024 + qsw * 8;
    const unsigned short* gb1 = B + (size_t)(n0 + 64 + mloc) * 1024 + qsw * 8;

    char* la0 = (char*)sA + tid * 16;
    char* la1 = (char*)sA + 4096 + tid * 16;
    char* lb0 = (char*)sB + tid * 16;
    char* lb1 = (char*)sB + 4096 + tid * 16;

    const int lane = tid & 63;
    const int wv   = tid >> 6;
    const int wm   = (wv & 1) * 64, wn = (wv >> 1) * 64;
    const int lr   = lane & 15, lq = lane >> 4;

    int sAidx[4], sBidx[4];
#pragma unroll
    for (int i = 0; i < 4; ++i) {
        int mi = wm + 16 * i + lr;
        sAidx[i] = mi * 4 + (lq ^ ((mi >> 1) & 3));
        int ni = wn + 16 * i + lr;
        sBidx[i] = ni * 4 + (lq ^ ((ni >> 1) & 3));
    }

    f32x4 acc[4][4] = {};

    for (int kt = 0; kt < KTOT; kt += 32) {
        __builtin_amdgcn_global_load_lds(
            (__attribute__((address_space(1))) void*)(void*)ga0,
            (__attribute__((address_space(3))) void*)la0, 16, 0, 0);
        __builtin_amdgcn_global_load_lds(
            (__attribute__((address_space(1))) void*)(void*)ga1,
            (__attribute__((address_space(3))) void*)la1, 16, 0, 0);
        __builtin_amdgcn_global_load_lds(
            (__attribute__((address_space(1))) void*)(void*)gb0,
            (__attribute__((address_space(3))) void*)lb0, 16, 0, 0);
        __builtin_amdgcn_global_load_lds(
            (__attribute__((address_space(1))) void*)(void*)gb1,
            (__attribute__((address_space(3))) void*)lb1, 16, 0, 0);
        ga0 += 32; ga1 += 32; gb0 += 32; gb1 += 32;
        __syncthreads();

        bf16x8 af[4], bfr[4];
#pragma unroll
        for (int i = 0; i < 4; ++i) af[i]  = __builtin_bit_cast(bf16x8, sA[sAidx[i]]);
#pragma unroll
        for (int j = 0; j < 4; ++j) bfr[j] = __builtin_bit_cast(bf16x8, sB[sBidx[j]]);

#pragma unroll
        for (int i = 0; i < 4; ++i)
#pragma unroll
            for (int j = 0; j < 4; ++j)
                acc[i][j] = __builtin_amdgcn_mfma_f32_16x16x32_bf16(af[i], bfr[j],
                                                                    acc[i][j], 0, 0, 0);
        __syncthreads();
    }

    // epilogue: C/D layout col=lane&15, row=(lane>>4)*4+r.
    // Transposed store: lane's 4 regs are 4 consecutive m -> one ushort4 (8B).
#pragma unroll
    for (int j = 0; j < 4; ++j) {
        int gn = n0 + wn + 16 * j + lr;
        float bj = bias[gn];
#pragma unroll
        for (int i = 0; i < 4; ++i) {
            int rowb = m0 + wm + 16 * i + lq * 4;
            alignas(8) unsigned short pk[4];
#pragma unroll
            for (int r = 0; r < 4; ++r) pk[r] = f2bf(acc[i][j][r] + bj);
            *(int2*)(GT + (size_t)gn * MTOT + rowb) = *(const int2*)pk;
        }
    }
}

// ---------------------------------------------------------------------------
// Scan, 3-kernel two-level decomposition.
// R1 lesson: lanes stride 64KB apart, so a lane's 128B chunk must NOT be consumed
// 16B-per-loop-iteration (line evicted before reuse -> 4x sector overfetch,
// FETCH=387MB). Fix: issue ALL chunk loads back-to-back into registers (in-flight
// same-line requests merge in TCC), then run the serial recurrence from registers.
// Also gives ~24 outstanding loads/thread for latency hiding.
//
// S1: per-chunk aggregates (P = prod f, C = fo-pool with c0=0).
//     Block = 256 thr = 32 h x 8 chunks; grid = 16b * 16hg * 4tg = 1024 blocks.
__global__ __launch_bounds__(256) void scan_part1(const unsigned short* __restrict__ GT,
                                                  float* __restrict__ Pws,
                                                  float* __restrict__ Cws) {
    const int tid   = threadIdx.x;
    const int h_loc = tid & 31;
    const int sc    = tid >> 5;           // 0..7
    const int bid   = blockIdx.x;
    const int tg    = bid & 3;
    const int hg    = (bid >> 2) & 15;
    const int b     = bid >> 6;
    const int h     = hg * 32 + h_loc;
    const int cg    = tg * 8 + sc;        // chunk index 0..31

    const size_t mbase = (size_t)b * TLEN + (size_t)cg * LC2;
    const unsigned short* gz = GT + (size_t)h * MTOT + mbase;
    const unsigned short* gf = GT + (size_t)(DCH + h) * MTOT + mbase;

    bf16x8 zv[8], fv[8];
#pragma unroll
    for (int q = 0; q < 8; ++q) zv[q] = *(const bf16x8*)(gz + q * 8);
#pragma unroll
    for (int q = 0; q < 8; ++q) fv[q] = *(const bf16x8*)(gf + q * 8);

    float P = 1.f, c = 0.f;
#pragma unroll
    for (int q = 0; q < 8; ++q)
#pragma unroll
        for (int r = 0; r < 8; ++r) {
            float f = sigmoidf_((float)fv[q][r]);
            float z = 2.f * sigmoidf_(2.f * (float)zv[q][r]) - 1.f;   // tanh
            c = f * c + (1.f - f) * z;
            P *= f;
        }
    const int ch = b * DCH + h;           // chain index, [cg][ch] layout -> coalesced
    Pws[(size_t)cg * CHAINS + ch] = P;
    Cws[(size_t)cg * CHAINS + ch] = c;
}

// S2: exclusive scan over the 32 chunk aggregates of each chain.
//     8192 chains, one thread each. All 64 inputs hoisted to registers first
//     (one latency burst instead of 32 serial round-trips).
__global__ __launch_bounds__(256) void scan_part2(const float* __restrict__ Pws,
                                                  const float* __restrict__ Cws,
                                                  float* __restrict__ Iws) {
    const int ch = blockIdx.x * 256 + threadIdx.x;   // 0..8191
    float Pv[NCH], Cv[NCH];
#pragma unroll
    for (int cg = 0; cg < NCH; ++cg) Pv[cg] = Pws[(size_t)cg * CHAINS + ch];
#pragma unroll
    for (int cg = 0; cg < NCH; ++cg) Cv[cg] = Cws[(size_t)cg * CHAINS + ch];
    float cc = 0.f;
#pragma unroll
    for (int cg = 0; cg < NCH; ++cg) {
        Iws[(size_t)cg * CHAINS + ch] = cc;
        cc = Pv[cg] * cc + Cv[cg];
    }
}

// S3: apply pass — recompute each chunk with the correct carry-in, write outputs.
//     Same register-blocked loads; nontemporal output stores (never re-read)
//     keep GT lines from being evicted from L2 by the store stream.
__global__ __launch_bounds__(256) void scan_part3(const unsigned short* __restrict__ GT,
                                                  const float* __restrict__ Iws,
                                                  float* __restrict__ out) {
    const int tid   = threadIdx.x;
    const int h_loc = tid & 31;
    const int sc    = tid >> 5;
    const int bid   = blockIdx.x;
    const int tg    = bid & 3;
    const int hg    = (bid >> 2) & 15;
    const int b     = bid >> 6;
    const int h     = hg * 32 + h_loc;
    const int cg    = tg * 8 + sc;

    const size_t mbase = (size_t)b * TLEN + (size_t)cg * LC2;
    const unsigned short* gz = GT + (size_t)h * MTOT + mbase;
    const unsigned short* gf = GT + (size_t)(DCH + h) * MTOT + mbase;
    const unsigned short* go = GT + (size_t)(2 * DCH + h) * MTOT + mbase;

    bf16x8 zv[8], fv[8], ov[8];
#pragma unroll
    for (int q = 0; q < 8; ++q) zv[q] = *(const bf16x8*)(gz + q * 8);
#pragma unroll
    for (int q = 0; q < 8; ++q) fv[q] = *(const bf16x8*)(gf + q * 8);
#pragma unroll
    for (int q = 0; q < 8; ++q) ov[q] = *(const bf16x8*)(go + q * 8);

    const int ch = b * DCH + h;
    float c = Iws[(size_t)cg * CHAINS + ch];

    const size_t BTH = (size_t)NB * TLEN * DCH;
    float* oC  = out + mbase * DCH + h;
    float* oOC = oC + BTH;
#pragma unroll
    for (int q = 0; q < 8; ++q)
#pragma unroll
        for (int r = 0; r < 8; ++r) {
            float f = sigmoidf_((float)fv[q][r]);
            float z = 2.f * sigmoidf_(2.f * (float)zv[q][r]) - 1.f;
            float o = sigmoidf_((float)ov[q][r]);
            c = f * c + (1.f - f) * z;
            __builtin_nontemporal_store(c,     oC  + (size_t)(q * 8 + r) * DCH);
            __builtin_nontemporal_store(o * c, oOC + (size_t)(q * 8 + r) * DCH);
        }
}

// ---------------------------------------------------------------------------
extern "C" void kernel_launch(void* const* d_in, const int* in_sizes, int n_in,
                              void* d_out, int out_size, void* d_ws, size_t ws_size,
                              hipStream_t stream) {
    const float* in   = (const float*)d_in[0];   // [16,2048,512] f32
    const float* w    = (const float*)d_in[1];   // [1536,512,2] f32
    const float* bias = (const float*)d_in[2];   // [1536] f32
    float* out = (float*)d_out;                  // [2][16,2048,512] f32

    unsigned short* Abf = (unsigned short*)d_ws;
    unsigned short* Bbf = Abf + (size_t)MTOT * 1024;
    unsigned short* GT  = Bbf + (size_t)NTOT * 1024;

    // scan scratch overlays Abf (dead after the GEMM): 3 * 1 MB
    float* Pws = (float*)d_ws;
    float* Cws = Pws + (size_t)NCH * CHAINS;
    float* Iws = Cws + (size_t)NCH * CHAINS;

    make_A<<<dim3(16384), dim3(256), 0, stream>>>(in, Abf);
    make_B<<<dim3(3072),  dim3(256), 0, stream>>>(w, Bbf);
    gemm_gates<<<dim3(3072), dim3(256), 0, stream>>>(Abf, Bbf, bias, GT);
    scan_part1<<<dim3(1024), dim3(256), 0, stream>>>(GT, Pws, Cws);
    scan_part2<<<dim3(CHAINS / 256), dim3(256), 0, stream>>>(Pws, Cws, Iws);
    scan_part3<<<dim3(1024), dim3(256), 0, stream>>>(GT, Iws, out);
}

// Round 3
// 400.353 us; speedup vs baseline: 1.2925x; 1.0456x over previous
//
#include <hip/hip_runtime.h>

// Problem: B=16, T=2048, D=512, H=512, K=2
// M = B*T = 32768 rows, GEMM K-dim = D*K = 1024, N = 3H = 1536.
//
// ws layout (bytes):
//   Abf [32768][1024] bf16 @ 0          (67,108,864)   -- dead after GEMM; scan
//                                                         scratch (P/C/I, 3MB) overlays it
//   Bbf [1536][1024]  bf16 @ 67108864   ( 3,145,728)
//   GT  [1536][32768] bf16 @ 70254592   (100,663,296)  pre-activation, TRANSPOSED
// total 170,917,888 B

#define MTOT 32768
#define NTOT 1536
#define KTOT 1024
#define DCH  512
#define TLEN 2048
#define NB   16

// scan decomposition: chunks of LC2 steps, two-level (aggregate / combine / apply)
#define LC2    64                 // t per chunk
#define NCH    32                 // TLEN / LC2
#define CHAINS 8192               // NB * DCH chains

// GEMM geometry: 256x256 tile, BK=32, 8 waves (2Mx4N), 4-deep LDS ring.
#define GBK 32
#define NKT (KTOT / GBK)          // 32 K-tiles

typedef __bf16 bf16x8 __attribute__((ext_vector_type(8)));
typedef float  f32x4  __attribute__((ext_vector_type(4)));

__device__ __forceinline__ unsigned short f2bf(float x) {
    unsigned u = __float_as_uint(x);
    u += 0x7FFFu + ((u >> 16) & 1u);   // round-to-nearest-even
    return (unsigned short)(u >> 16);
}
__device__ __forceinline__ float bf2f(unsigned short h) {
    return __uint_as_float(((unsigned)h) << 16);
}
__device__ __forceinline__ float sigmoidf_(float x) {
    return 1.f / (1.f + __expf(-x));
}

// ---------------------------------------------------------------------------
// K0: build A bf16 [M][1024]: A[m][j] = in[(m-1)*512 + j], zero when t==0 && j<512
__global__ __launch_bounds__(256) void make_A(const float* __restrict__ in,
                                              unsigned short* __restrict__ A) {
    size_t i = (size_t)blockIdx.x * 256 + threadIdx.x;
    size_t e = i * 8;
    size_t m = e >> 10;
    int    j = (int)(e & 1023);
    alignas(16) unsigned short h[8];
    if (((m & (TLEN - 1)) == 0) && (j < DCH)) {
#pragma unroll
        for (int r = 0; r < 8; ++r) h[r] = 0;
    } else {
        const float* src = in + ((long long)m - 1) * DCH + j;
        float4 a = *(const float4*)src;
        float4 b = *(const float4*)(src + 4);
        h[0] = f2bf(a.x); h[1] = f2bf(a.y); h[2] = f2bf(a.z); h[3] = f2bf(a.w);
        h[4] = f2bf(b.x); h[5] = f2bf(b.y); h[6] = f2bf(b.z); h[7] = f2bf(b.w);
    }
    *(int4*)(A + e) = *(const int4*)h;
}

// ---------------------------------------------------------------------------
// K1: build B bf16 [N][1024]: Bt[o][kc*512 + d] = w[o*1024 + d*2 + kc]
__global__ __launch_bounds__(256) void make_B(const float* __restrict__ w,
                                              unsigned short* __restrict__ Bt) {
    int i = blockIdx.x * 256 + threadIdx.x;     // 1536*512 = 786432
    int o = i >> 9, d = i & 511;
    float w0 = w[(size_t)(o * 512 + d) * 2];
    float w1 = w[(size_t)(o * 512 + d) * 2 + 1];
    Bt[(size_t)o * 1024 + d]       = f2bf(w0);
    Bt[(size_t)o * 1024 + 512 + d] = f2bf(w1);
}

// ---------------------------------------------------------------------------
// K2: GEMM, output TRANSPOSED: GT[n][m] = sum_k A[m][k]*Bt[n][k] + bias[n] (bf16)
//
// 256x256 tile, BK=32, 512 threads = 8 waves (2M x 4N), per-wave 128x64 output.
// 4-deep LDS ring (4 x 32KB = 128 KiB), prefetch distance 3, counted
// s_waitcnt vmcnt(8) at tile top (never drains to 0 in the loop), raw s_barrier
// (NOT __syncthreads, which force-drains vmcnt(0) -- the stall this removes).
// 32 MFMA per barrier. LDS bank swizzle quad' = lq ^ ((row>>1)&3) folded into
// the GLOBAL source address (LDS stays lane-linear for global_load_lds).
//
// Ring safety: stage for tile t+3 writes buf[(t+3)&3] == buf[(t-1)&3]; every
// wave's tile t-1 ds_reads completed (compiler lgkmcnt before MFMA) before it
// reached tile t's barrier, and the stage is issued after that barrier.
// Per-wave FIFO: at tile-t top, outstanding = tiles t,t+1,t+2 (12 loads);
// vmcnt(8) drains exactly tile t's 4.
//
// XCD swizzle: grid 768 = 8 * 96, bijective; 6 consecutive blocks share an
// A panel (512KB) within one XCD's L2.
__global__ __launch_bounds__(512) void gemm_gates(const unsigned short* __restrict__ A,
                                                  const unsigned short* __restrict__ B,
                                                  const float* __restrict__ bias,
                                                  unsigned short* __restrict__ GT) {
    __shared__ int4 lds4[8192];   // 4 bufs x (A 256x32 16KB + B 256x32 16KB)

    const int tid = threadIdx.x;
    const int bx0 = blockIdx.x;
    const int bx  = (bx0 & 7) * 96 + (bx0 >> 3);
    const int mT  = bx / 6, nT = bx % 6;
    const int m0  = mT * 256, n0 = nT * 256;

    // staging source pointers (bank swizzle pre-applied to global k-group)
    const int r0 = tid >> 2, q = tid & 3;
    const int qs = q ^ ((r0 >> 1) & 3);
    const unsigned short* ga0 = A + (size_t)(m0 + r0) * 1024 + qs * 8;
    const unsigned short* ga1 = A + (size_t)(m0 + 128 + r0) * 1024 + qs * 8;
    const unsigned short* gb0 = B + (size_t)(n0 + r0) * 1024 + qs * 8;
    const unsigned short* gb1 = B + (size_t)(n0 + 128 + r0) * 1024 + qs * 8;
    char* ldsc = (char*)lds4;

    const int lane = tid & 63;
    const int wv   = tid >> 6;
    const int wm   = wv >> 2, wn = wv & 3;     // 2 x 4 wave grid
    const int lr   = lane & 15, lq = lane >> 4;

    // ds_read indices (int4 units within a buffer): row*4 + swizzled quad
    int aidx[2][4], bidx[4];
#pragma unroll
    for (int h = 0; h < 2; ++h)
#pragma unroll
        for (int i = 0; i < 4; ++i) {
            int row = wm * 128 + h * 64 + i * 16 + lr;
            aidx[h][i] = row * 4 + (lq ^ ((row >> 1) & 3));
        }
#pragma unroll
    for (int j = 0; j < 4; ++j) {
        int col = wn * 64 + j * 16 + lr;
        bidx[j] = 1024 + col * 4 + (lq ^ ((col >> 1) & 3));   // B at +16KB
    }

    f32x4 acc[8][4] = {};

#define GLL(SRC, DOFF) __builtin_amdgcn_global_load_lds( \
        (__attribute__((address_space(1))) void*)(void*)(SRC), \
        (__attribute__((address_space(3))) void*)(ldsc + (DOFF)), 16, 0, 0)

#define STAGE_A(U) { const int bb_ = ((U) & 3) * 32768; \
        GLL(ga0 + (size_t)(U) * GBK, bb_ + tid * 16); \
        GLL(ga1 + (size_t)(U) * GBK, bb_ + 8192 + tid * 16); }
#define STAGE_B(U) { const int bb_ = ((U) & 3) * 32768; \
        GLL(gb0 + (size_t)(U) * GBK, bb_ + 16384 + tid * 16); \
        GLL(gb1 + (size_t)(U) * GBK, bb_ + 24576 + tid * 16); }

    // prologue: stage tiles 0,1,2 (12 loads in flight)
    STAGE_A(0); STAGE_B(0);
    STAGE_A(1); STAGE_B(1);
    STAGE_A(2); STAGE_B(2);

#define TILE(T, VW, DO_STAGE) { \
        asm volatile("s_waitcnt vmcnt(" VW ")" ::: "memory"); \
        __builtin_amdgcn_s_barrier(); \
        __builtin_amdgcn_sched_barrier(0); \
        const int bufo = ((T) & 3) * 2048; \
        bf16x8 bf[4], af[4]; \
        _Pragma("unroll") \
        for (int j = 0; j < 4; ++j) bf[j] = __builtin_bit_cast(bf16x8, lds4[bufo + bidx[j]]); \
        _Pragma("unroll") \
        for (int i = 0; i < 4; ++i) af[i] = __builtin_bit_cast(bf16x8, lds4[bufo + aidx[0][i]]); \
        if (DO_STAGE) STAGE_A((T) + 3); \
        __builtin_amdgcn_s_setprio(1); \
        _Pragma("unroll") \
        for (int i = 0; i < 4; ++i) \
            _Pragma("unroll") \
            for (int j = 0; j < 4; ++j) \
                acc[i][j] = __builtin_amdgcn_mfma_f32_16x16x32_bf16(af[i], bf[j], acc[i][j], 0, 0, 0); \
        __builtin_amdgcn_s_setprio(0); \
        _Pragma("unroll") \
        for (int i = 0; i < 4; ++i) af[i] = __builtin_bit_cast(bf16x8, lds4[bufo + aidx[1][i]]); \
        if (DO_STAGE) STAGE_B((T) + 3); \
        __builtin_amdgcn_s_setprio(1); \
        _Pragma("unroll") \
        for (int i = 0; i < 4; ++i) \
            _Pragma("unroll") \
            for (int j = 0; j < 4; ++j) \
                acc[4 + i][j] = __builtin_amdgcn_mfma_f32_16x16x32_bf16(af[i], bf[j], acc[4 + i][j], 0, 0, 0); \
        __builtin_amdgcn_s_setprio(0); }

    for (int t = 0; t < NKT - 3; ++t)   // t = 0..28, stages tiles 3..31
        TILE(t, "8", 1);
    TILE(NKT - 3, "8", 0);              // t=29: 12 outstanding -> drain t29's 4
    TILE(NKT - 2, "4", 0);              // t=30:  8 outstanding -> drain t30's 4
    TILE(NKT - 1, "0", 0);              // t=31: drain the rest

#undef TILE
#undef STAGE_A
#undef STAGE_B
#undef GLL

    // epilogue: C/D layout col(n)=lane&15, row(m)=(lane>>4)*4+r.
    // acc[i][j]: i=0..3 rows wm*128+i*16 (phase h0), i=4..7 rows wm*128+64+(i-4)*16
    //            == wm*128 + i*16 for all i.  4 consecutive m -> int2 store.
#pragma unroll
    for (int j = 0; j < 4; ++j) {
        int gn = n0 + wn * 64 + j * 16 + lr;
        float bj = bias[gn];
#pragma unroll
        for (int i = 0; i < 8; ++i) {
            int gm = m0 + wm * 128 + i * 16 + lq * 4;
            alignas(8) unsigned short pk[4];
#pragma unroll
            for (int r = 0; r < 4; ++r) pk[r] = f2bf(acc[i][j][r] + bj);
            *(int2*)(GT + (size_t)gn * MTOT + gm) = *(const int2*)pk;
        }
    }
}

// ---------------------------------------------------------------------------
// Scan, 3-kernel two-level decomposition.
// R1 lesson: lanes stride 64KB apart, so a lane's 128B chunk must NOT be consumed
// 16B-per-loop-iteration (line evicted before reuse -> 4x sector overfetch,
// FETCH=387MB). Fix: issue ALL chunk loads back-to-back into registers (in-flight
// same-line requests merge in TCC), then run the serial recurrence from registers.
//
// S1: per-chunk aggregates (P = prod f, C = fo-pool with c0=0).
//     Block = 256 thr = 32 h x 8 chunks; grid = 16b * 16hg * 4tg = 1024 blocks.
__global__ __launch_bounds__(256) void scan_part1(const unsigned short* __restrict__ GT,
                                                  float* __restrict__ Pws,
                                                  float* __restrict__ Cws) {
    const int tid   = threadIdx.x;
    const int h_loc = tid & 31;
    const int sc    = tid >> 5;           // 0..7
    const int bid   = blockIdx.x;
    const int tg    = bid & 3;
    const int hg    = (bid >> 2) & 15;
    const int b     = bid >> 6;
    const int h     = hg * 32 + h_loc;
    const int cg    = tg * 8 + sc;        // chunk index 0..31

    const size_t mbase = (size_t)b * TLEN + (size_t)cg * LC2;
    const unsigned short* gz = GT + (size_t)h * MTOT + mbase;
    const unsigned short* gf = GT + (size_t)(DCH + h) * MTOT + mbase;

    bf16x8 zv[8], fv[8];
#pragma unroll
    for (int q = 0; q < 8; ++q) zv[q] = *(const bf16x8*)(gz + q * 8);
#pragma unroll
    for (int q = 0; q < 8; ++q) fv[q] = *(const bf16x8*)(gf + q * 8);

    float P = 1.f, c = 0.f;
#pragma unroll
    for (int q = 0; q < 8; ++q)
#pragma unroll
        for (int r = 0; r < 8; ++r) {
            float f = sigmoidf_((float)fv[q][r]);
            float z = 2.f * sigmoidf_(2.f * (float)zv[q][r]) - 1.f;   // tanh
            c = f * c + (1.f - f) * z;
            P *= f;
        }
    const int ch = b * DCH + h;           // chain index, [cg][ch] layout -> coalesced
    Pws[(size_t)cg * CHAINS + ch] = P;
    Cws[(size_t)cg * CHAINS + ch] = c;
}

// S2: exclusive scan over the 32 chunk aggregates of each chain.
//     8192 chains, one thread each. All 64 inputs hoisted to registers first
//     (one latency burst instead of 32 serial round-trips).
__global__ __launch_bounds__(256) void scan_part2(const float* __restrict__ Pws,
                                                  const float* __restrict__ Cws,
                                                  float* __restrict__ Iws) {
    const int ch = blockIdx.x * 256 + threadIdx.x;   // 0..8191
    float Pv[NCH], Cv[NCH];
#pragma unroll
    for (int cg = 0; cg < NCH; ++cg) Pv[cg] = Pws[(size_t)cg * CHAINS + ch];
#pragma unroll
    for (int cg = 0; cg < NCH; ++cg) Cv[cg] = Cws[(size_t)cg * CHAINS + ch];
    float cc = 0.f;
#pragma unroll
    for (int cg = 0; cg < NCH; ++cg) {
        Iws[(size_t)cg * CHAINS + ch] = cc;
        cc = Pv[cg] * cc + Cv[cg];
    }
}

// S3: apply pass — recompute each chunk with the correct carry-in, write outputs.
//     Register-blocked loads; nontemporal output stores (never re-read).
__global__ __launch_bounds__(256) void scan_part3(const unsigned short* __restrict__ GT,
                                                  const float* __restrict__ Iws,
                                                  float* __restrict__ out) {
    const int tid   = threadIdx.x;
    const int h_loc = tid & 31;
    const int sc    = tid >> 5;
    const int bid   = blockIdx.x;
    const int tg    = bid & 3;
    const int hg    = (bid >> 2) & 15;
    const int b     = bid >> 6;
    const int h     = hg * 32 + h_loc;
    const int cg    = tg * 8 + sc;

    const size_t mbase = (size_t)b * TLEN + (size_t)cg * LC2;
    const unsigned short* gz = GT + (size_t)h * MTOT + mbase;
    const unsigned short* gf = GT + (size_t)(DCH + h) * MTOT + mbase;
    const unsigned short* go = GT + (size_t)(2 * DCH + h) * MTOT + mbase;

    bf16x8 zv[8], fv[8], ov[8];
#pragma unroll
    for (int q = 0; q < 8; ++q) zv[q] = *(const bf16x8*)(gz + q * 8);
#pragma unroll
    for (int q = 0; q < 8; ++q) fv[q] = *(const bf16x8*)(gf + q * 8);
#pragma unroll
    for (int q = 0; q < 8; ++q) ov[q] = *(const bf16x8*)(go + q * 8);

    const int ch = b * DCH + h;
    float c = Iws[(size_t)cg * CHAINS + ch];

    const size_t BTH = (size_t)NB * TLEN * DCH;
    float* oC  = out + mbase * DCH + h;
    float* oOC = oC + BTH;
#pragma unroll
    for (int q = 0; q < 8; ++q)
#pragma unroll
        for (int r = 0; r < 8; ++r) {
            float f = sigmoidf_((float)fv[q][r]);
            float z = 2.f * sigmoidf_(2.f * (float)zv[q][r]) - 1.f;
            float o = sigmoidf_((float)ov[q][r]);
            c = f * c + (1.f - f) * z;
            __builtin_nontemporal_store(c,     oC  + (size_t)(q * 8 + r) * DCH);
            __builtin_nontemporal_store(o * c, oOC + (size_t)(q * 8 + r) * DCH);
        }
}

// ---------------------------------------------------------------------------
extern "C" void kernel_launch(void* const* d_in, const int* in_sizes, int n_in,
                              void* d_out, int out_size, void* d_ws, size_t ws_size,
                              hipStream_t stream) {
    const float* in   = (const float*)d_in[0];   // [16,2048,512] f32
    const float* w    = (const float*)d_in[1];   // [1536,512,2] f32
    const float* bias = (const float*)d_in[2];   // [1536] f32
    float* out = (float*)d_out;                  // [2][16,2048,512] f32

    unsigned short* Abf = (unsigned short*)d_ws;
    unsigned short* Bbf = Abf + (size_t)MTOT * 1024;
    unsigned short* GT  = Bbf + (size_t)NTOT * 1024;

    // scan scratch overlays Abf (dead after the GEMM): 3 * 1 MB
    float* Pws = (float*)d_ws;
    float* Cws = Pws + (size_t)NCH * CHAINS;
    float* Iws = Cws + (size_t)NCH * CHAINS;

    make_A<<<dim3(16384), dim3(256), 0, stream>>>(in, Abf);
    make_B<<<dim3(3072),  dim3(256), 0, stream>>>(w, Bbf);
    gemm_gates<<<dim3(768), dim3(512), 0, stream>>>(Abf, Bbf, bias, GT);
    scan_part1<<<dim3(1024), dim3(256), 0, stream>>>(GT, Pws, Cws);
    scan_part2<<<dim3(CHAINS / 256), dim3(256), 0, stream>>>(Pws, Cws, Iws);
    scan_part3<<<dim3(1024), dim3(256), 0, stream>>>(GT, Iws, out);
}